// Round 1
// baseline (273.367 us; speedup 1.0000x reference)
//
#include <hip/hip_runtime.h>

// SpectralPooling: x (4,64,64,64,32) f32 -> out (4,32,32,32,32) f32.
// DCT64 -> trunc 24 -> pad 32 -> iDCT32 along each of D,H,W collapses to one
// 32x64 matrix A per axis (same A for all three axes).
// Pipeline:
//   k0: compute A (32x64) in ws           (double precision, 8 KB)
//   k1: y1[b][p][hwc]  = A @ x[b][d][hwc]     (batch 4,  N=131072)
//   k2: y2[bp][q][wc]  = A @ y1[bp][h][wc]    (batch 128, N=2048)
//   k3: out[b][r][q][p][c] = sum_w A[r][w] y2[b][p][q][w][c]  (+transpose)
// ws layout: A (2048 f) | y1 (16777216 f, 64 MiB) | y2 (8388608 f, 32 MiB)
// ws required: ~96.1 MiB

#define PI_D 3.14159265358979323846

__global__ __launch_bounds__(256) void sp_compute_A(float* __restrict__ A) {
    int idx = blockIdx.x * 256 + threadIdx.x;   // 0..2047
    if (idx >= 2048) return;
    int o = idx >> 6;   // 0..31 (output index)
    int i = idx & 63;   // 0..63 (input index)
    double acc = 0.0;
    for (int p = 0; p < 24; ++p) {
        double s32 = (p == 0) ? sqrt(1.0 / 32.0) : sqrt(2.0 / 32.0);
        double s64 = (p == 0) ? sqrt(1.0 / 64.0) : sqrt(2.0 / 64.0);
        acc += s32 * cos(PI_D * (o + 0.5) * p / 32.0)
             * s64 * cos(PI_D * (i + 0.5) * p / 64.0);
    }
    A[idx] = (float)acc;
}

// Y[b][p][n] = sum_k A[p][k] * X[b][k][n]   (p=0..31, k=0..63)
// blockIdx.y = batch b; each thread owns one float2 column (2 n's).
__global__ __launch_bounds__(256) void sp_contract(
        const float* __restrict__ X, const float* __restrict__ Amat,
        float* __restrict__ Y, int N) {
    __shared__ float As[64][32];           // As[k][p] = A[p][k]
    int t = threadIdx.x;
    for (int i = t; i < 2048; i += 256) {
        int p = i >> 6, k = i & 63;
        As[k][p] = Amat[i];
    }
    __syncthreads();

    long b  = blockIdx.y;
    long n2 = (long)blockIdx.x * 256 + t;  // float2 index within batch
    long s2 = (long)(N >> 1);              // float2 stride per k

    const float2* xp = (const float2*)X + b * 64 * s2 + n2;

    float2 acc[32];
#pragma unroll
    for (int p = 0; p < 32; ++p) acc[p] = make_float2(0.f, 0.f);

    for (int k = 0; k < 64; ++k) {
        float2 xv = xp[(long)k * s2];
        const float4* Arow = (const float4*)&As[k][0];
#pragma unroll
        for (int pg = 0; pg < 8; ++pg) {
            float4 a4 = Arow[pg];
            acc[pg * 4 + 0].x += a4.x * xv.x; acc[pg * 4 + 0].y += a4.x * xv.y;
            acc[pg * 4 + 1].x += a4.y * xv.x; acc[pg * 4 + 1].y += a4.y * xv.y;
            acc[pg * 4 + 2].x += a4.z * xv.x; acc[pg * 4 + 2].y += a4.z * xv.y;
            acc[pg * 4 + 3].x += a4.w * xv.x; acc[pg * 4 + 3].y += a4.w * xv.y;
        }
    }

    float2* yp = (float2*)Y + b * 32 * s2 + n2;
#pragma unroll
    for (int p = 0; p < 32; ++p) yp[(long)p * s2] = acc[p];
}

// out[b][r][q][p][c] = sum_w A[r][w] * y2[b][p][q][w][c]
// j = ((b*32+p)*32+q) in [0,4096); 8 j's per block, thread = (j_local, c).
__global__ __launch_bounds__(256) void sp_contract_w_transpose(
        const float* __restrict__ Y2, const float* __restrict__ Amat,
        float* __restrict__ Out) {
    __shared__ float As[64][32];           // As[w][r] = A[r][w]
    int t = threadIdx.x;
    for (int i = t; i < 2048; i += 256) {
        int r = i >> 6, w = i & 63;
        As[w][r] = Amat[i];
    }
    __syncthreads();

    int j = blockIdx.x * 8 + (t >> 5);     // (b,p,q) flat index
    int c = t & 31;
    int b = j >> 10;
    int p = (j >> 5) & 31;
    int q = j & 31;

    const float* src = Y2 + (long)j * 2048 + c;   // [j][w][c], w stride 32

    float acc[32];
#pragma unroll
    for (int r = 0; r < 32; ++r) acc[r] = 0.f;

    for (int w = 0; w < 64; ++w) {
        float xv = src[w * 32];
        const float4* Arow = (const float4*)&As[w][0];
#pragma unroll
        for (int rg = 0; rg < 8; ++rg) {
            float4 a4 = Arow[rg];
            acc[rg * 4 + 0] += a4.x * xv;
            acc[rg * 4 + 1] += a4.y * xv;
            acc[rg * 4 + 2] += a4.z * xv;
            acc[rg * 4 + 3] += a4.w * xv;
        }
    }

    // out index: (((b*32 + r)*32 + q)*32 + p)*32 + c
    float* dst = Out + ((long)(b * 1024 + q)) * 1024 + p * 32 + c;
#pragma unroll
    for (int r = 0; r < 32; ++r) {
        dst[(long)r * 32768] = acc[r];
    }
}

extern "C" void kernel_launch(void* const* d_in, const int* in_sizes, int n_in,
                              void* d_out, int out_size, void* d_ws, size_t ws_size,
                              hipStream_t stream) {
    const float* x = (const float*)d_in[0];         // 4*64*64*64*32 = 33,554,432 f32
    float* out = (float*)d_out;                     // 4*32*32*32*32 = 4,194,304 f32

    float* A  = (float*)d_ws;                       // 2048 floats
    float* y1 = A + 2048;                           // 4*32*64*64*32 = 16,777,216 f32
    float* y2 = y1 + 16777216;                      // 4*32*32*64*32 =  8,388,608 f32

    // k0: build the fused DCT->trunc->iDCT matrix (32x64)
    sp_compute_A<<<8, 256, 0, stream>>>(A);

    // k1: contract D.  batch=4, K=64, N=64*64*32=131072.  grid (131072/2/256, 4)
    sp_contract<<<dim3(256, 4), 256, 0, stream>>>(x, A, y1, 131072);

    // k2: contract H.  batch=4*32=128, K=64, N=64*32=2048. grid (2048/2/256, 128)
    sp_contract<<<dim3(4, 128), 256, 0, stream>>>(y1, A, y2, 2048);

    // k3: contract W + transposed writeout. 4096 (b,p,q) / 8 per block
    sp_contract_w_transpose<<<512, 256, 0, stream>>>(y2, A, out);
}